// Round 11
// baseline (358.640 us; speedup 1.0000x reference)
//
#include <hip/hip_runtime.h>

// Problem constants: V=27, E=64, H=128, B=256, S=512 (enc and dec)
#define V_ 27
#define E_ 64
#define H_ 128
#define S_ 512
#define SCL 2.8853900817779268f   // 2*log2(e): tanh(z) = 1 - 2/(exp2(SCL*z)+1)

typedef float f32x2 __attribute__((ext_vector_type(2)));
typedef float f32x4 __attribute__((ext_vector_type(4)));

// Barrier WITHOUT vmcnt drain: LDS visibility only. Global stores stay in flight.
#define BAR() asm volatile("s_waitcnt lgkmcnt(0)\n\ts_barrier" ::: "memory")

// ---- packed fp32 FMA (v_pk_fma_f32 on gfx950; fp32-exact) ----
#if __has_builtin(__builtin_elementwise_fma)
#define EFMA(H2, W2, A) (A) = __builtin_elementwise_fma((f32x2)(H2), (f32x2)(W2), (A))
#else
#define EFMA(H2, W2, A) do { f32x2 _h = (H2), _w = (W2); \
    (A).x = fmaf(_h.x, _w.x, (A).x); (A).y = fmaf(_h.y, _w.y, (A).y); } while (0)
#endif
#define LO2(Q) __builtin_shufflevector((Q), (Q), 0, 1)
#define HI2(Q) __builtin_shufflevector((Q), (Q), 2, 3)

// Per-iteration register pins: force weight residency (defeat load remat/sinking).
#define PINW() asm volatile("" : "+v"(WA[0]), "+v"(WA[1]), "+v"(WA[2]), "+v"(WA[3]), \
                                 "+v"(WA[4]), "+v"(WA[5]), "+v"(WA[6]), "+v"(WA[7]), \
                                 "+v"(WB[0]), "+v"(WB[1]), "+v"(WB[2]), "+v"(WB[3]), \
                                 "+v"(WB[4]), "+v"(WB[5]), "+v"(WB[6]), "+v"(WB[7]))
#define PIND() asm volatile("" : "+v"(DQ[0]), "+v"(DQ[1]), "+v"(DQ[2]), "+v"(DQ[3]))

// Hazard-safe DPP add (compiler inserts required wait states; raw asm DPP does not).
template<int CTRL>
__device__ __forceinline__ float dpp_add(float x) {
    int y = __builtin_amdgcn_update_dpp(0, __builtin_bit_cast(int, x), CTRL, 0xF, 0xF, true);
    return x + __builtin_bit_cast(float, y);
}
#define QP_1032 0xB1   // quad_perm [1,0,3,2]  (xor 1)
#define QP_2301 0x4E   // quad_perm [2,3,0,1]  (xor 2)
#define RR8 0x128      // row_ror:8 == xor 8 within a 16-lane row

// tanh from pre-scaled argument P = SCL*z:  tanh(z) = 1 - 2/(exp2(P)+1)
__device__ __forceinline__ float tanh_ps(float P) {
#if __has_builtin(__builtin_amdgcn_exp2f)
    float e = __builtin_amdgcn_exp2f(P);
#else
    float e = __expf(P * 0.69314718055994531f);
#endif
#if __has_builtin(__builtin_amdgcn_rcpf)
    float q = __builtin_amdgcn_rcpf(e + 1.0f);
    return fmaf(-2.0f, q, 1.0f);
#else
    return 1.0f - __fdividef(2.0f, e + 1.0f);
#endif
}

// k-pair weight quads (pre-scaled by SCL):
//   WA[i] = { W[16kk+2i][j0],   W[16kk+2i+1][j0],   W[16kk+2i][j0+1], W[16kk+2i+1][j0+1] }
//   WB[i] = same for cols j0+2, j0+3
#define LOADW(WH) do {                                                   \
    _Pragma("unroll")                                                    \
    for (int i = 0; i < 8; ++i) {                                        \
        const float* _a = (WH) + (16 * kk + 2 * i) * H_ + j0;            \
        f32x4 ra = *(const f32x4*)(_a);                                  \
        f32x4 rb = *(const f32x4*)(_a + H_);                             \
        WA[i] = (f32x4){ra.x * SCL, rb.x * SCL, ra.y * SCL, rb.y * SCL}; \
        WB[i] = (f32x4){ra.z * SCL, rb.z * SCL, ra.w * SCL, rb.w * SCL}; \
    }                                                                    \
} while (0)

// One k-pair: P0..P3 accumulate {even,odd}-k products for cols j0..j0+3
#define ACCP(HP, I) do { f32x2 _hp = (HP);              \
    EFMA(_hp, LO2(WA[I]), P0); EFMA(_hp, HI2(WA[I]), P1); \
    EFMA(_hp, LO2(WB[I]), P2); EFMA(_hp, HI2(WB[I]), P3); } while (0)

// One RNN step, software-pipelined: consumes h(t-1) carried in HA..HD, writes h(t)
// to WBUF, barriers, then IMMEDIATELY issues next-h + next-T + next-id LDS reads;
// the read window is filled with the dense dot (old H regs).
// IDP2 = &ids[t+2] (sentinel-padded, always valid). TLB = LDS T-table base.
#define RNN_STEP(WBUF, DENSEF, IDP2, TLB, DOSTORE, OUTP) do {                       \
    PINW();                                                                         \
    if (DENSEF) PIND();                                                             \
    f32x2 P0 = {0,0}, P1 = {0,0}, P2 = {0,0}, P3 = {0,0};                           \
    ACCP(LO2(HA), 0); ACCP(HI2(HA), 1); ACCP(LO2(HB), 2); ACCP(HI2(HB), 3);         \
    ACCP(LO2(HC), 4); ACCP(HI2(HC), 5); ACCP(LO2(HD), 6); ACCP(HI2(HD), 7);         \
    float s0 = P0.x + P0.y, s1 = P1.x + P1.y;                                       \
    float s2 = P2.x + P2.y, s3 = P3.x + P3.y;                                       \
    s0 = dpp_add<QP_2301>(dpp_add<QP_1032>(s0));                                    \
    s1 = dpp_add<QP_2301>(dpp_add<QP_1032>(s1));                                    \
    s2 = dpp_add<QP_2301>(dpp_add<QP_1032>(s2));                                    \
    s3 = dpp_add<QP_2301>(dpp_add<QP_1032>(s3));                                    \
    float s01 = c1 ? s1 : s0;                                                       \
    float s23 = c1 ? s3 : s2;                                                       \
    float r   = c2 ? s23 : s01;                                                     \
    r = dpp_add<RR8>(r);                                 /* xor8 = kk bit2 */       \
    float hnew = tanh_ps(r + Tv);                                                   \
    if (wrlane) (WBUF)[wrword] = hnew;    /* single writer per column (b32) */      \
    BAR();                                                                          \
    const f32x4* hbp = (const f32x4*)((WBUF) + 20 * kk);                            \
    f32x4 N0 = hbp[0], N1 = hbp[1], N2 = hbp[2], N3 = hbp[3]; /* next-h reads */    \
    float Tv_n = (TLB)[id_next * H_ + jd];               /* next-T (LDS) */         \
    int   id_n2 = (IDP2)[0];                             /* ids[t+2] (LDS) */       \
    if (DENSEF) {                                        /* fills read window */    \
        f32x2 E0 = {0,0}, E1 = {0,0};                                               \
        EFMA(LO2(HA), LO2(DQ[0]), E0); EFMA(HI2(HA), HI2(DQ[0]), E1);               \
        EFMA(LO2(HB), LO2(DQ[1]), E0); EFMA(HI2(HB), HI2(DQ[1]), E1);               \
        EFMA(LO2(HC), LO2(DQ[2]), E0); EFMA(HI2(HC), HI2(DQ[2]), E1);               \
        EFMA(LO2(HD), LO2(DQ[3]), E0); EFMA(HI2(HD), HI2(DQ[3]), E1);               \
        f32x2 E = E0 + E1;                                                          \
        float d = E.x + E.y;                                                        \
        d = dpp_add<RR8>(dpp_add<QP_2301>(dpp_add<QP_1032>(d)));                    \
        if (DOSTORE) (OUTP)[0] = d + db;                 /* vmcnt never drained */  \
    }                                                                               \
    HA = N0; HB = N1; HC = N2; HD = N3;                                             \
    id_next = id_n2;                                                                \
    Tv = Tv_n;                                                                      \
} while (0)

__global__ __attribute__((amdgpu_flat_work_group_size(256, 256), amdgpu_waves_per_eu(1, 1)))
void seq2seq_rnn_kernel(const int* __restrict__ enc_ids, const int* __restrict__ dec_ids,
                        const float* __restrict__ embed,
                        const float* __restrict__ enc_Wx, const float* __restrict__ enc_b,
                        const float* __restrict__ enc_Wh, const float* __restrict__ dec_Wx,
                        const float* __restrict__ dec_b,  const float* __restrict__ dec_Wh,
                        const float* __restrict__ dense_W, const float* __restrict__ dense_b,
                        float* __restrict__ out) {
    __shared__ __align__(16) float lds_h0[160];          // 8 groups of 16, stride 20
    __shared__ __align__(16) float lds_h1[160];
    __shared__ __align__(16) int   lds_ids[2 * S_ + 2];
    __shared__ __align__(16) float lds_T[2 * V_ * H_];   // both T tables, 27648 B

    const int tid  = threadIdx.x;
    const int b    = blockIdx.x;
    const int lane = tid & 63;
    const int w    = tid >> 6;                                    // 0..3
    // K-split index kk (8 chunks of 16 h-values): lane bits {0,1,3} -> DPP-reducible
    const int kk   = (lane & 3) | (((lane >> 3) & 1) << 2);
    // column-group index jl: lane bits {2,4,5}
    const int jl   = ((lane >> 2) & 1) | (((lane >> 4) & 3) << 1);
    const int j0     = (w << 5) + (jl << 2);                      // 4 cols per thread
    const int jd     = j0 + (lane & 3);                           // this lane's column
    const int wrword = 20 * (jd >> 4) + (jd & 15);                // stride-20 layout
    const bool wrlane = (lane & 8) == 0;                          // one writer per column
    const bool c1 = (lane & 1) != 0;
    const bool c2 = (lane & 2) != 0;
    const int vd   = (w << 3) | jl;               // dense logit slot (27 of 32 used)

    // ---- stage ids ----
    if (tid < 128) ((int4*)lds_ids)[tid] = ((const int4*)(enc_ids + b * S_))[tid];
    else ((int4*)(lds_ids + S_))[tid - 128] = ((const int4*)(dec_ids + b * S_))[tid - 128];
    if (tid < 2) lds_ids[2 * S_ + tid] = 0;
    if (tid < 160) lds_h0[tid] = 0.0f;

    // ---- fused prep: T[tbl][v][j] = SCL*(b[j] + sum_e embed[v][e]*Wx[e][j]) ----
    // tid<128 -> encoder table (tbl 0), tid>=128 -> decoder table (tbl 1); j = tid&127.
    // Wx column preloaded coalesced; embed rows are wave-uniform (scalar loads).
    {
        const int   jT  = tid & 127;
        const float* Wx = (tid < 128) ? enc_Wx : dec_Wx;
        const float* bb = (tid < 128) ? enc_b  : dec_b;
        float* Tdst = lds_T + (tid >> 7) * (V_ * H_) + jT;
        float wx[E_];
        #pragma unroll
        for (int e = 0; e < E_; ++e) wx[e] = Wx[e * H_ + jT];
        float bj = bb[jT];
        for (int v = 0; v < V_; ++v) {
            float s = bj;
            #pragma unroll
            for (int e = 0; e < E_; ++e) s = fmaf(embed[v * E_ + e], wx[e], s);
            Tdst[v * H_] = s * SCL;
        }
    }

    // ---- recurrent weights: k-pair packed quads, 64 VGPRs, pre-scaled by SCL ----
    f32x4 WA[8], WB[8];
    LOADW(enc_Wh);

    // ---- dense weights: DQ[j] = dW[16kk+4j .. +3][vd] (4 rows per quad, unscaled) ----
    f32x4 DQ[4]; float db = 0.0f;
    {
        int vc = (vd < V_) ? vd : 0;
        const float* dp = dense_W + (16 * kk) * V_ + vc;
        DQ[0] = (f32x4){dp[ 0 * V_], dp[ 1 * V_], dp[ 2 * V_], dp[ 3 * V_]};
        DQ[1] = (f32x4){dp[ 4 * V_], dp[ 5 * V_], dp[ 6 * V_], dp[ 7 * V_]};
        DQ[2] = (f32x4){dp[ 8 * V_], dp[ 9 * V_], dp[10 * V_], dp[11 * V_]};
        DQ[3] = (f32x4){dp[12 * V_], dp[13 * V_], dp[14 * V_], dp[15 * V_]};
        if (vd < V_) db = dense_b[vd];
    }
    const bool dlane = ((lane & 11) == 0) && (vd < V_);    // kk==0 lanes (one writer)
    float* outd = out + b * (S_ * V_) + vd;
    __syncthreads();   // ids + T + h0 ready

    // ---- carried h registers: pre-read h(-1)=0 from lds_h0 ----
    f32x4 HA, HB, HC, HD;
    {
        const f32x4* hbp = (const f32x4*)(lds_h0 + 20 * kk);
        HA = hbp[0]; HB = hbp[1]; HC = hbp[2]; HD = hbp[3];
    }

    // ================= encoder: 512 steps =================
    // Step s writes buf[(s+1)&1]: even->lds_h1, odd->lds_h0 (pre-read used lds_h0).
    {
        int   id_next = lds_ids[1];
        float Tv      = lds_T[lds_ids[0] * H_ + jd];
        for (int t = 0; t < S_; t += 2) {
            RNN_STEP(lds_h1, false, lds_ids + t + 2, lds_T, false, (float*)out);
            RNN_STEP(lds_h0, false, lds_ids + t + 3, lds_T, false, (float*)out);
        }
    }

    // ---- swap to decoder recurrent weights (H regs = enc state, preserved) ----
    LOADW(dec_Wh);

    // ================= decoder: 512 steps; dense piggybacked =================
    // Step t's dense consumes h(t-1) (carried regs) -> out[(t-1)*V].
    {
        const int* ids_d = lds_ids + S_;
        float*     Td    = lds_T + V_ * H_;
        int   id_next = ids_d[1];
        float Tv      = Td[ids_d[0] * H_ + jd];
        for (int t = 0; t < S_; t += 2) {
            RNN_STEP(lds_h1, true, ids_d + t + 2, Td,
                     dlane && (t > 0), outd + (t - 1) * V_);
            RNN_STEP(lds_h0, true, ids_d + t + 3, Td,
                     dlane, outd + t * V_);
        }
    }

    // epilogue: dense on final state h(511) — already in HA..HD (no LDS read)
    {
        f32x2 E0 = {0,0}, E1 = {0,0};
        EFMA(LO2(HA), LO2(DQ[0]), E0); EFMA(HI2(HA), HI2(DQ[0]), E1);
        EFMA(LO2(HB), LO2(DQ[1]), E0); EFMA(HI2(HB), HI2(DQ[1]), E1);
        EFMA(LO2(HC), LO2(DQ[2]), E0); EFMA(HI2(HC), HI2(DQ[2]), E1);
        EFMA(LO2(HD), LO2(DQ[3]), E0); EFMA(HI2(HD), HI2(DQ[3]), E1);
        f32x2 E = E0 + E1;
        float d = E.x + E.y;
        d = dpp_add<RR8>(dpp_add<QP_2301>(dpp_add<QP_1032>(d)));
        if (dlane) outd[(S_ - 1) * V_] = d + db;
    }
}

extern "C" void kernel_launch(void* const* d_in, const int* in_sizes, int n_in,
                              void* d_out, int out_size, void* d_ws, size_t ws_size,
                              hipStream_t stream) {
    const int*   enc_ids = (const int*)d_in[0];
    const int*   dec_ids = (const int*)d_in[1];
    const float* embed   = (const float*)d_in[2];
    const float* enc_Wx  = (const float*)d_in[3];
    const float* enc_Wh  = (const float*)d_in[4];
    const float* enc_b   = (const float*)d_in[5];
    const float* dec_Wx  = (const float*)d_in[6];
    const float* dec_Wh  = (const float*)d_in[7];
    const float* dec_b   = (const float*)d_in[8];
    const float* dense_W = (const float*)d_in[9];
    const float* dense_b = (const float*)d_in[10];
    float* out = (float*)d_out;

    hipLaunchKernelGGL(seq2seq_rnn_kernel, dim3(256), dim3(256), 0, stream,
                       enc_ids, dec_ids, embed, enc_Wx, enc_b, enc_Wh,
                       dec_Wx, dec_b, dec_Wh, dense_W, dense_b, out);
}

// Round 12
// 334.804 us; speedup vs baseline: 1.0712x; 1.0712x over previous
//
#include <hip/hip_runtime.h>

// Problem constants: V=27, E=64, H=128, B=256, S=512 (enc and dec)
#define V_ 27
#define E_ 64
#define H_ 128
#define S_ 512
#define SCL 2.8853900817779268f   // 2*log2(e): tanh(z) = 1 - 2/(exp2(SCL*z)+1)

typedef float f32x2 __attribute__((ext_vector_type(2)));
typedef float f32x4 __attribute__((ext_vector_type(4)));

// Barrier WITHOUT vmcnt drain: LDS visibility only. Global stores stay in flight.
#define BAR() asm volatile("s_waitcnt lgkmcnt(0)\n\ts_barrier" ::: "memory")

// ---- packed fp32 FMA (v_pk_fma_f32 on gfx950; fp32-exact) ----
#if __has_builtin(__builtin_elementwise_fma)
#define EFMA(H2, W2, A) (A) = __builtin_elementwise_fma((f32x2)(H2), (f32x2)(W2), (A))
#else
#define EFMA(H2, W2, A) do { f32x2 _h = (H2), _w = (W2); \
    (A).x = fmaf(_h.x, _w.x, (A).x); (A).y = fmaf(_h.y, _w.y, (A).y); } while (0)
#endif
#define LO2(Q) __builtin_shufflevector((Q), (Q), 0, 1)
#define HI2(Q) __builtin_shufflevector((Q), (Q), 2, 3)

// Per-iteration register pins: force weight residency (defeat load remat/sinking).
#define PINW() asm volatile("" : "+v"(WA[0]), "+v"(WA[1]), "+v"(WA[2]), "+v"(WA[3]), \
                                 "+v"(WA[4]), "+v"(WA[5]), "+v"(WA[6]), "+v"(WA[7]), \
                                 "+v"(WB[0]), "+v"(WB[1]), "+v"(WB[2]), "+v"(WB[3]), \
                                 "+v"(WB[4]), "+v"(WB[5]), "+v"(WB[6]), "+v"(WB[7]))
#define PIND() asm volatile("" : "+v"(DQ[0]), "+v"(DQ[1]), "+v"(DQ[2]), "+v"(DQ[3]))

// Hazard-safe DPP add (compiler inserts required wait states; raw asm DPP does not).
template<int CTRL>
__device__ __forceinline__ float dpp_add(float x) {
    int y = __builtin_amdgcn_update_dpp(0, __builtin_bit_cast(int, x), CTRL, 0xF, 0xF, true);
    return x + __builtin_bit_cast(float, y);
}
#define QP_1032 0xB1   // quad_perm [1,0,3,2]  (xor 1)
#define QP_2301 0x4E   // quad_perm [2,3,0,1]  (xor 2)
#define RR8 0x128      // row_ror:8 == xor 8 within a 16-lane row

// tanh from pre-scaled argument P = SCL*z:  tanh(z) = 1 - 2/(exp2(P)+1)
__device__ __forceinline__ float tanh_ps(float P) {
#if __has_builtin(__builtin_amdgcn_exp2f)
    float e = __builtin_amdgcn_exp2f(P);
#else
    float e = __expf(P * 0.69314718055994531f);
#endif
#if __has_builtin(__builtin_amdgcn_rcpf)
    float q = __builtin_amdgcn_rcpf(e + 1.0f);
    return fmaf(-2.0f, q, 1.0f);
#else
    return 1.0f - __fdividef(2.0f, e + 1.0f);
#endif
}

// ---------- prep kernel: T[tbl][v][j] = SCL*(b[j] + sum_e embed[v][e]*Wx[e][j]) ----------
__global__ void prep_T(const float* __restrict__ embed,
                       const float* __restrict__ eWx, const float* __restrict__ eb,
                       const float* __restrict__ dWx, const float* __restrict__ db_,
                       float* __restrict__ Tg) {
    int tbl = blockIdx.x / V_;
    int v   = blockIdx.x - tbl * V_;
    int j   = threadIdx.x;
    const float* Wx = tbl ? dWx : eWx;
    const float* bb = tbl ? db_ : eb;
    float s = bb[j];
    #pragma unroll
    for (int e = 0; e < E_; ++e) s = fmaf(embed[v * E_ + e], Wx[e * H_ + j], s);
    Tg[tbl * V_ * H_ + v * H_ + j] = s * SCL;
}

// k-pair weight quads (pre-scaled by SCL):
//   WA[i] = { W[16kk+2i][j0],   W[16kk+2i+1][j0],   W[16kk+2i][j0+1], W[16kk+2i+1][j0+1] }
//   WB[i] = same for cols j0+2, j0+3
#define LOADW(WH) do {                                                   \
    _Pragma("unroll")                                                    \
    for (int i = 0; i < 8; ++i) {                                        \
        const float* _a = (WH) + (16 * kk + 2 * i) * H_ + j0;            \
        f32x4 ra = *(const f32x4*)(_a);                                  \
        f32x4 rb = *(const f32x4*)(_a + H_);                             \
        WA[i] = (f32x4){ra.x * SCL, rb.x * SCL, ra.y * SCL, rb.y * SCL}; \
        WB[i] = (f32x4){ra.z * SCL, rb.z * SCL, ra.w * SCL, rb.w * SCL}; \
    }                                                                    \
} while (0)

// One k-pair: P0..P3 accumulate {even,odd}-k products for cols j0..j0+3
#define ACCP(HP, I) do { f32x2 _hp = (HP);              \
    EFMA(_hp, LO2(WA[I]), P0); EFMA(_hp, HI2(WA[I]), P1); \
    EFMA(_hp, LO2(WB[I]), P2); EFMA(_hp, HI2(WB[I]), P3); } while (0)

// One RNN step, software-pipelined: consumes h(t-1) carried in HA..HD, writes h(t)
// to WBUF, barriers, then IMMEDIATELY issues next-h + next-T + next-id LDS reads;
// the read window is filled with the dense dot (old H regs).
// IDP2 = &ids[t+2] (sentinel-padded, always valid). TLB = LDS T-table base.
#define RNN_STEP(WBUF, DENSEF, IDP2, TLB, DOSTORE, OUTP) do {                       \
    PINW();                                                                         \
    if (DENSEF) PIND();                                                             \
    f32x2 P0 = {0,0}, P1 = {0,0}, P2 = {0,0}, P3 = {0,0};                           \
    ACCP(LO2(HA), 0); ACCP(HI2(HA), 1); ACCP(LO2(HB), 2); ACCP(HI2(HB), 3);         \
    ACCP(LO2(HC), 4); ACCP(HI2(HC), 5); ACCP(LO2(HD), 6); ACCP(HI2(HD), 7);         \
    float s0 = P0.x + P0.y, s1 = P1.x + P1.y;                                       \
    float s2 = P2.x + P2.y, s3 = P3.x + P3.y;                                       \
    s0 = dpp_add<QP_2301>(dpp_add<QP_1032>(s0));                                    \
    s1 = dpp_add<QP_2301>(dpp_add<QP_1032>(s1));                                    \
    s2 = dpp_add<QP_2301>(dpp_add<QP_1032>(s2));                                    \
    s3 = dpp_add<QP_2301>(dpp_add<QP_1032>(s3));                                    \
    float s01 = c1 ? s1 : s0;                                                       \
    float s23 = c1 ? s3 : s2;                                                       \
    float r   = c2 ? s23 : s01;                                                     \
    r = dpp_add<RR8>(r);                                 /* xor8 = kk bit2 */       \
    float hnew = tanh_ps(r + Tv);                                                   \
    if (wrlane) (WBUF)[wrword] = hnew;    /* single writer per column (b32) */      \
    BAR();                                                                          \
    const f32x4* hbp = (const f32x4*)((WBUF) + 20 * kk);                            \
    f32x4 N0 = hbp[0], N1 = hbp[1], N2 = hbp[2], N3 = hbp[3]; /* next-h reads */    \
    float Tv_n = (TLB)[id_next * H_ + jd];               /* next-T (LDS) */         \
    int   id_n2 = (IDP2)[0];                             /* ids[t+2] (LDS) */       \
    if (DENSEF) {                                        /* fills read window */    \
        f32x2 E0 = {0,0}, E1 = {0,0};                                               \
        EFMA(LO2(HA), LO2(DQ[0]), E0); EFMA(HI2(HA), HI2(DQ[0]), E1);               \
        EFMA(LO2(HB), LO2(DQ[1]), E0); EFMA(HI2(HB), HI2(DQ[1]), E1);               \
        EFMA(LO2(HC), LO2(DQ[2]), E0); EFMA(HI2(HC), HI2(DQ[2]), E1);               \
        EFMA(LO2(HD), LO2(DQ[3]), E0); EFMA(HI2(HD), HI2(DQ[3]), E1);               \
        f32x2 E = E0 + E1;                                                          \
        float d = E.x + E.y;                                                        \
        d = dpp_add<RR8>(dpp_add<QP_2301>(dpp_add<QP_1032>(d)));                    \
        if (DOSTORE) (OUTP)[0] = d + db;                 /* vmcnt never drained */  \
    }                                                                               \
    HA = N0; HB = N1; HC = N2; HD = N3;                                             \
    id_next = id_n2;                                                                \
    Tv = Tv_n;                                                                      \
} while (0)

__global__ __attribute__((amdgpu_flat_work_group_size(256, 256), amdgpu_waves_per_eu(1, 1)))
void seq2seq_rnn_kernel(const int* __restrict__ enc_ids, const int* __restrict__ dec_ids,
                        const float* __restrict__ enc_Wh, const float* __restrict__ dec_Wh,
                        const float* __restrict__ dense_W, const float* __restrict__ dense_b,
                        const float* __restrict__ Tg,      // [2][27][128] in d_ws (SCL-scaled)
                        float* __restrict__ out) {
    __shared__ __align__(16) float lds_h0[160];          // 8 groups of 16, stride 20
    __shared__ __align__(16) float lds_h1[160];
    __shared__ __align__(16) int   lds_ids[2 * S_ + 2];
    __shared__ __align__(16) float lds_T[2 * V_ * H_];   // both T tables, 27648 B

    const int tid  = threadIdx.x;
    const int b    = blockIdx.x;
    const int lane = tid & 63;
    const int w    = tid >> 6;                                    // 0..3
    // K-split index kk (8 chunks of 16 h-values): lane bits {0,1,3} -> DPP-reducible
    const int kk   = (lane & 3) | (((lane >> 3) & 1) << 2);
    // column-group index jl: lane bits {2,4,5}
    const int jl   = ((lane >> 2) & 1) | (((lane >> 4) & 3) << 1);
    const int j0     = (w << 5) + (jl << 2);                      // 4 cols per thread
    const int jd     = j0 + (lane & 3);                           // this lane's column
    const int wrword = 20 * (jd >> 4) + (jd & 15);                // stride-20 layout
    const bool wrlane = (lane & 8) == 0;                          // one writer per column
    const bool c1 = (lane & 1) != 0;
    const bool c2 = (lane & 2) != 0;
    const int vd   = (w << 3) | jl;               // dense logit slot (27 of 32 used)

    // ---- stage ids; T tables; zero h0 ----
    if (tid < 128) ((int4*)lds_ids)[tid] = ((const int4*)(enc_ids + b * S_))[tid];
    else ((int4*)(lds_ids + S_))[tid - 128] = ((const int4*)(dec_ids + b * S_))[tid - 128];
    if (tid < 2) lds_ids[2 * S_ + tid] = 0;
    #pragma unroll
    for (int i = 0; i < 7; ++i) {                // 2*27*128/4 = 1728 quads
        int idx = tid + 256 * i;
        if (idx < 2 * V_ * H_ / 4) ((f32x4*)lds_T)[idx] = ((const f32x4*)Tg)[idx];
    }
    if (tid < 160) lds_h0[tid] = 0.0f;

    // ---- recurrent weights: k-pair packed quads, 64 VGPRs, pre-scaled by SCL ----
    f32x4 WA[8], WB[8];
    LOADW(enc_Wh);

    // ---- dense weights: DQ[j] = dW[16kk+4j .. +3][vd] (4 rows per quad, unscaled) ----
    f32x4 DQ[4]; float db = 0.0f;
    {
        int vc = (vd < V_) ? vd : 0;
        const float* dp = dense_W + (16 * kk) * V_ + vc;
        DQ[0] = (f32x4){dp[ 0 * V_], dp[ 1 * V_], dp[ 2 * V_], dp[ 3 * V_]};
        DQ[1] = (f32x4){dp[ 4 * V_], dp[ 5 * V_], dp[ 6 * V_], dp[ 7 * V_]};
        DQ[2] = (f32x4){dp[ 8 * V_], dp[ 9 * V_], dp[10 * V_], dp[11 * V_]};
        DQ[3] = (f32x4){dp[12 * V_], dp[13 * V_], dp[14 * V_], dp[15 * V_]};
        if (vd < V_) db = dense_b[vd];
    }
    const bool dlane = ((lane & 11) == 0) && (vd < V_);    // kk==0 lanes (one writer)
    float* outd = out + b * (S_ * V_) + vd;
    __syncthreads();   // ids + T + h0 ready

    // ---- carried h registers: pre-read h(-1)=0 from lds_h0 ----
    f32x4 HA, HB, HC, HD;
    {
        const f32x4* hbp = (const f32x4*)(lds_h0 + 20 * kk);
        HA = hbp[0]; HB = hbp[1]; HC = hbp[2]; HD = hbp[3];
    }

    // ================= encoder: 512 steps =================
    // Step s writes buf[(s+1)&1]: even->lds_h1, odd->lds_h0 (pre-read used lds_h0).
    // (Stale prefetches at the segment end are discarded by decoder re-init.)
    {
        int   id_next = lds_ids[1];
        float Tv      = lds_T[lds_ids[0] * H_ + jd];
        for (int t = 0; t < S_; t += 2) {
            RNN_STEP(lds_h1, false, lds_ids + t + 2, lds_T, false, (float*)out);
            RNN_STEP(lds_h0, false, lds_ids + t + 3, lds_T, false, (float*)out);
        }
    }

    // ---- swap to decoder recurrent weights (H regs = enc state, preserved) ----
    LOADW(dec_Wh);

    // ================= decoder: 512 steps; dense piggybacked =================
    // Step t's dense consumes h(t-1) (carried regs) -> out[(t-1)*V].
    {
        const int* ids_d = lds_ids + S_;
        float*     Td    = lds_T + V_ * H_;
        int   id_next = ids_d[1];
        float Tv      = Td[ids_d[0] * H_ + jd];
        for (int t = 0; t < S_; t += 2) {
            RNN_STEP(lds_h1, true, ids_d + t + 2, Td,
                     dlane && (t > 0), outd + (t - 1) * V_);
            RNN_STEP(lds_h0, true, ids_d + t + 3, Td,
                     dlane, outd + t * V_);
        }
    }

    // epilogue: dense on final state h(511) — already in HA..HD (no LDS read)
    {
        f32x2 E0 = {0,0}, E1 = {0,0};
        EFMA(LO2(HA), LO2(DQ[0]), E0); EFMA(HI2(HA), HI2(DQ[0]), E1);
        EFMA(LO2(HB), LO2(DQ[1]), E0); EFMA(HI2(HB), HI2(DQ[1]), E1);
        EFMA(LO2(HC), LO2(DQ[2]), E0); EFMA(HI2(HC), HI2(DQ[2]), E1);
        EFMA(LO2(HD), LO2(DQ[3]), E0); EFMA(HI2(HD), HI2(DQ[3]), E1);
        f32x2 E = E0 + E1;
        float d = E.x + E.y;
        d = dpp_add<RR8>(dpp_add<QP_2301>(dpp_add<QP_1032>(d)));
        if (dlane) outd[(S_ - 1) * V_] = d + db;
    }
}

extern "C" void kernel_launch(void* const* d_in, const int* in_sizes, int n_in,
                              void* d_out, int out_size, void* d_ws, size_t ws_size,
                              hipStream_t stream) {
    const int*   enc_ids = (const int*)d_in[0];
    const int*   dec_ids = (const int*)d_in[1];
    const float* embed   = (const float*)d_in[2];
    const float* enc_Wx  = (const float*)d_in[3];
    const float* enc_Wh  = (const float*)d_in[4];
    const float* enc_b   = (const float*)d_in[5];
    const float* dec_Wx  = (const float*)d_in[6];
    const float* dec_Wh  = (const float*)d_in[7];
    const float* dec_b   = (const float*)d_in[8];
    const float* dense_W = (const float*)d_in[9];
    const float* dense_b = (const float*)d_in[10];
    float* out = (float*)d_out;
    float* Tg  = (float*)d_ws;   // 2*27*128 floats = 27648 B

    hipLaunchKernelGGL(prep_T, dim3(2 * V_), dim3(H_), 0, stream,
                       embed, enc_Wx, enc_b, dec_Wx, dec_b, Tg);
    hipLaunchKernelGGL(seq2seq_rnn_kernel, dim3(256), dim3(256), 0, stream,
                       enc_ids, dec_ids, enc_Wh, dec_Wh, dense_W, dense_b, Tg, out);
}

// Round 13
// 329.745 us; speedup vs baseline: 1.0876x; 1.0153x over previous
//
#include <hip/hip_runtime.h>

// Problem constants: V=27, E=64, H=128, B=256, S=512 (enc and dec)
#define V_ 27
#define E_ 64
#define H_ 128
#define S_ 512
#define SCL 2.8853900817779268f   // 2*log2(e): tanh(z) = 1 - 2/(exp2(SCL*z)+1)

typedef float f32x2 __attribute__((ext_vector_type(2)));
typedef float f32x4 __attribute__((ext_vector_type(4)));

// Barrier WITHOUT vmcnt drain: LDS visibility only. Global stores stay in flight.
#define BAR() asm volatile("s_waitcnt lgkmcnt(0)\n\ts_barrier" ::: "memory")

// ---- packed fp32 FMA (v_pk_fma_f32 on gfx950; fp32-exact) ----
#if __has_builtin(__builtin_elementwise_fma)
#define EFMA(H2, W2, A) (A) = __builtin_elementwise_fma((f32x2)(H2), (f32x2)(W2), (A))
#else
#define EFMA(H2, W2, A) do { f32x2 _h = (H2), _w = (W2); \
    (A).x = fmaf(_h.x, _w.x, (A).x); (A).y = fmaf(_h.y, _w.y, (A).y); } while (0)
#endif
#define LO2(Q) __builtin_shufflevector((Q), (Q), 0, 1)
#define HI2(Q) __builtin_shufflevector((Q), (Q), 2, 3)

// Per-iteration register pins: force weight residency (defeat load remat/sinking).
#define PINW() asm volatile("" : "+v"(WA[0]), "+v"(WA[1]), "+v"(WA[2]), "+v"(WA[3]), \
                                 "+v"(WA[4]), "+v"(WA[5]), "+v"(WA[6]), "+v"(WA[7]), \
                                 "+v"(WB[0]), "+v"(WB[1]), "+v"(WB[2]), "+v"(WB[3]), \
                                 "+v"(WB[4]), "+v"(WB[5]), "+v"(WB[6]), "+v"(WB[7]))
#define PIND() asm volatile("" : "+v"(DQ[0]), "+v"(DQ[1]), "+v"(DQ[2]), "+v"(DQ[3]))

// Hazard-safe DPP add (compiler inserts required wait states; raw asm DPP does not).
template<int CTRL>
__device__ __forceinline__ float dpp_add(float x) {
    int y = __builtin_amdgcn_update_dpp(0, __builtin_bit_cast(int, x), CTRL, 0xF, 0xF, true);
    return x + __builtin_bit_cast(float, y);
}
#define QP_1032 0xB1   // quad_perm [1,0,3,2]  (xor 1)
#define QP_2301 0x4E   // quad_perm [2,3,0,1]  (xor 2)
#define RR8 0x128      // row_ror:8 == xor 8 within a 16-lane row

// tanh from pre-scaled argument P = SCL*z:  tanh(z) = 1 - 2/(exp2(P)+1)
__device__ __forceinline__ float tanh_ps(float P) {
#if __has_builtin(__builtin_amdgcn_exp2f)
    float e = __builtin_amdgcn_exp2f(P);
#else
    float e = __expf(P * 0.69314718055994531f);
#endif
#if __has_builtin(__builtin_amdgcn_rcpf)
    float q = __builtin_amdgcn_rcpf(e + 1.0f);
    return fmaf(-2.0f, q, 1.0f);
#else
    return 1.0f - __fdividef(2.0f, e + 1.0f);
#endif
}

// ---------- prep kernel: T[tbl][v][j] = SCL*(b[j] + sum_e embed[v][e]*Wx[e][j]) ----------
__global__ void prep_T(const float* __restrict__ embed,
                       const float* __restrict__ eWx, const float* __restrict__ eb,
                       const float* __restrict__ dWx, const float* __restrict__ db_,
                       float* __restrict__ Tg) {
    int tbl = blockIdx.x / V_;
    int v   = blockIdx.x - tbl * V_;
    int j   = threadIdx.x;
    const float* Wx = tbl ? dWx : eWx;
    const float* bb = tbl ? db_ : eb;
    float s = bb[j];
    #pragma unroll
    for (int e = 0; e < E_; ++e) s = fmaf(embed[v * E_ + e], Wx[e * H_ + j], s);
    Tg[tbl * V_ * H_ + v * H_ + j] = s * SCL;
}

// k-pair weight quads (pre-scaled by SCL):
//   WA[i] = { W[16kk+2i][j0],   W[16kk+2i+1][j0],   W[16kk+2i][j0+1], W[16kk+2i+1][j0+1] }
//   WB[i] = same for cols j0+2, j0+3
#define LOADW(WH) do {                                                   \
    _Pragma("unroll")                                                    \
    for (int i = 0; i < 8; ++i) {                                        \
        const float* _a = (WH) + (16 * kk + 2 * i) * H_ + j0;            \
        f32x4 ra = *(const f32x4*)(_a);                                  \
        f32x4 rb = *(const f32x4*)(_a + H_);                             \
        WA[i] = (f32x4){ra.x * SCL, rb.x * SCL, ra.y * SCL, rb.y * SCL}; \
        WB[i] = (f32x4){ra.z * SCL, rb.z * SCL, ra.w * SCL, rb.w * SCL}; \
    }                                                                    \
} while (0)

// One k-pair: P0..P3 accumulate {even,odd}-k products for cols j0..j0+3
#define ACCP(HP, I) do { f32x2 _hp = (HP);              \
    EFMA(_hp, LO2(WA[I]), P0); EFMA(_hp, HI2(WA[I]), P1); \
    EFMA(_hp, LO2(WB[I]), P2); EFMA(_hp, HI2(WB[I]), P3); } while (0)

// One RNN step, software-pipelined: consumes h(t-1) carried in HA..HD, writes h(t)
// to WBUF, barriers, then IMMEDIATELY issues next-h + next-T LDS reads; the read
// window is filled with the dense dot (old H regs) and id bookkeeping.
// TLB = LDS T-table base (float*), all-LDS per-step loads.
#define RNN_STEP(WBUF, DENSEF, LOADPAIRF, IDP, TLB, DOSTORE, OUTP) do {             \
    PINW();                                                                         \
    if (DENSEF) PIND();                                                             \
    f32x2 P0 = {0,0}, P1 = {0,0}, P2 = {0,0}, P3 = {0,0};                           \
    ACCP(LO2(HA), 0); ACCP(HI2(HA), 1); ACCP(LO2(HB), 2); ACCP(HI2(HB), 3);         \
    ACCP(LO2(HC), 4); ACCP(HI2(HC), 5); ACCP(LO2(HD), 6); ACCP(HI2(HD), 7);         \
    float s0 = P0.x + P0.y, s1 = P1.x + P1.y;                                       \
    float s2 = P2.x + P2.y, s3 = P3.x + P3.y;                                       \
    s0 = dpp_add<QP_2301>(dpp_add<QP_1032>(s0));                                    \
    s1 = dpp_add<QP_2301>(dpp_add<QP_1032>(s1));                                    \
    s2 = dpp_add<QP_2301>(dpp_add<QP_1032>(s2));                                    \
    s3 = dpp_add<QP_2301>(dpp_add<QP_1032>(s3));                                    \
    float s01 = c1 ? s1 : s0;                                                       \
    float s23 = c1 ? s3 : s2;                                                       \
    float r   = c2 ? s23 : s01;                                                     \
    r = dpp_add<RR8>(r);                                 /* xor8 = kk bit2 */       \
    float hnew = tanh_ps(r + Tv);                                                   \
    if (wrlane) (WBUF)[wrword] = hnew;    /* single writer per column (b32) */      \
    BAR();                                                                          \
    const f32x4* hbp = (const f32x4*)((WBUF) + 20 * kk);                            \
    f32x4 N0 = hbp[0], N1 = hbp[1], N2 = hbp[2], N3 = hbp[3]; /* next-h reads */    \
    float Tv_n = (TLB)[id_next * H_ + jd];               /* next-T (LDS) */         \
    int2 idpr_n = idpr;                                                             \
    if (LOADPAIRF) idpr_n = *(const int2*)((IDP) + 2);   /* ids[t+2..t+3], b64 */   \
    if (DENSEF) {                                        /* fills read window */    \
        f32x2 E0 = {0,0}, E1 = {0,0};                                               \
        EFMA(LO2(HA), LO2(DQ[0]), E0); EFMA(HI2(HA), HI2(DQ[0]), E1);               \
        EFMA(LO2(HB), LO2(DQ[1]), E0); EFMA(HI2(HB), HI2(DQ[1]), E1);               \
        EFMA(LO2(HC), LO2(DQ[2]), E0); EFMA(HI2(HC), HI2(DQ[2]), E1);               \
        EFMA(LO2(HD), LO2(DQ[3]), E0); EFMA(HI2(HD), HI2(DQ[3]), E1);               \
        f32x2 E = E0 + E1;                                                          \
        float d = E.x + E.y;                                                        \
        d = dpp_add<RR8>(dpp_add<QP_2301>(dpp_add<QP_1032>(d)));                    \
        if (DOSTORE) (OUTP)[0] = d + db;                 /* vmcnt never drained */  \
    }                                                                               \
    HA = N0; HB = N1; HC = N2; HD = N3;                                             \
    if (LOADPAIRF) { idpr = idpr_n; id_next = idpr_n.x; }                           \
    else           { id_next = idpr.y; }                                            \
    Tv = Tv_n;                                                                      \
} while (0)

__global__ __attribute__((amdgpu_flat_work_group_size(256, 256), amdgpu_waves_per_eu(1, 1)))
void seq2seq_rnn_kernel(const int* __restrict__ enc_ids, const int* __restrict__ dec_ids,
                        const float* __restrict__ enc_Wh, const float* __restrict__ dec_Wh,
                        const float* __restrict__ dense_W, const float* __restrict__ dense_b,
                        const float* __restrict__ Tg,      // [2][27][128] in d_ws (SCL-scaled)
                        float* __restrict__ out) {
    __shared__ __align__(16) float lds_h0[160];          // 8 groups of 16, stride 20
    __shared__ __align__(16) float lds_h1[160];
    __shared__ __align__(16) int   lds_ids[2 * S_ + 2];
    __shared__ __align__(16) float lds_T[2 * V_ * H_];   // both T tables, 27648 B

    const int tid  = threadIdx.x;
    const int b    = blockIdx.x;
    const int lane = tid & 63;
    const int w    = tid >> 6;                                    // 0..3
    // K-split index kk (8 chunks of 16 h-values): lane bits {0,1,3} -> DPP-reducible
    const int kk   = (lane & 3) | (((lane >> 3) & 1) << 2);
    // column-group index jl: lane bits {2,4,5}
    const int jl   = ((lane >> 2) & 1) | (((lane >> 4) & 3) << 1);
    const int j0     = (w << 5) + (jl << 2);                      // 4 cols per thread
    const int jd     = j0 + (lane & 3);                           // this lane's column
    const int wrword = 20 * (jd >> 4) + (jd & 15);                // stride-20 layout
    const bool wrlane = (lane & 8) == 0;                          // one writer per column
    const bool c1 = (lane & 1) != 0;
    const bool c2 = (lane & 2) != 0;
    const int vd   = (w << 3) | jl;               // dense logit slot (27 of 32 used)

    // ---- stage ids; T tables; zero h0 ----
    if (tid < 128) ((int4*)lds_ids)[tid] = ((const int4*)(enc_ids + b * S_))[tid];
    else ((int4*)(lds_ids + S_))[tid - 128] = ((const int4*)(dec_ids + b * S_))[tid - 128];
    if (tid < 2) lds_ids[2 * S_ + tid] = 0;
    #pragma unroll
    for (int i = 0; i < 7; ++i) {                // 2*27*128/4 = 1728 quads
        int idx = tid + 256 * i;
        if (idx < 2 * V_ * H_ / 4) ((f32x4*)lds_T)[idx] = ((const f32x4*)Tg)[idx];
    }
    if (tid < 160) lds_h0[tid] = 0.0f;

    // ---- recurrent weights: k-pair packed quads, 64 VGPRs, pre-scaled by SCL ----
    f32x4 WA[8], WB[8];
    LOADW(enc_Wh);

    // ---- dense weights: DQ[j] = dW[16kk+4j .. +3][vd] (4 rows per quad, unscaled) ----
    f32x4 DQ[4]; float db = 0.0f;
    {
        int vc = (vd < V_) ? vd : 0;
        const float* dp = dense_W + (16 * kk) * V_ + vc;
        DQ[0] = (f32x4){dp[ 0 * V_], dp[ 1 * V_], dp[ 2 * V_], dp[ 3 * V_]};
        DQ[1] = (f32x4){dp[ 4 * V_], dp[ 5 * V_], dp[ 6 * V_], dp[ 7 * V_]};
        DQ[2] = (f32x4){dp[ 8 * V_], dp[ 9 * V_], dp[10 * V_], dp[11 * V_]};
        DQ[3] = (f32x4){dp[12 * V_], dp[13 * V_], dp[14 * V_], dp[15 * V_]};
        if (vd < V_) db = dense_b[vd];
    }
    const bool dlane = ((lane & 11) == 0) && (vd < V_);    // kk==0 lanes (one writer)
    float* outd = out + b * (S_ * V_) + vd;
    __syncthreads();   // ids + T + h0 ready

    // ---- carried h registers: pre-read h(-1)=0 from lds_h0 ----
    f32x4 HA, HB, HC, HD;
    {
        const f32x4* hbp = (const f32x4*)(lds_h0 + 20 * kk);
        HA = hbp[0]; HB = hbp[1]; HC = hbp[2]; HD = hbp[3];
    }

    // ================= encoder: 512 steps =================
    // Step s writes buf[(s+1)&1]: even->lds_h1, odd->lds_h0 (pre-read used lds_h0).
    {
        int2  idpr = make_int2(0, 0);
        int   id_next = lds_ids[1];
        float Tv      = lds_T[lds_ids[0] * H_ + jd];
        for (int t = 0; t < S_; t += 2) {
            RNN_STEP(lds_h1, false, true,  lds_ids + t, lds_T, false, (float*)out);
            RNN_STEP(lds_h0, false, false, lds_ids + t, lds_T, false, (float*)out);
        }
    }

    // ---- swap to decoder recurrent weights (H regs = enc state, preserved) ----
    LOADW(dec_Wh);

    // ================= decoder: 512 steps; dense piggybacked =================
    // Step t's dense consumes h(t-1) (carried regs) -> out[(t-1)*V].
    {
        const int* ids_d = lds_ids + S_;
        float*     Td    = lds_T + V_ * H_;
        int2  idpr = make_int2(0, 0);
        int   id_next = ids_d[1];
        float Tv      = Td[ids_d[0] * H_ + jd];
        for (int t = 0; t < S_; t += 2) {
            RNN_STEP(lds_h1, true, true,  ids_d + t, Td,
                     dlane && (t > 0), outd + (t - 1) * V_);
            RNN_STEP(lds_h0, true, false, ids_d + t, Td,
                     dlane, outd + t * V_);
        }
    }

    // epilogue: dense on final state h(511) — already in HA..HD (no LDS read)
    {
        f32x2 E0 = {0,0}, E1 = {0,0};
        EFMA(LO2(HA), LO2(DQ[0]), E0); EFMA(HI2(HA), HI2(DQ[0]), E1);
        EFMA(LO2(HB), LO2(DQ[1]), E0); EFMA(HI2(HB), HI2(DQ[1]), E1);
        EFMA(LO2(HC), LO2(DQ[2]), E0); EFMA(HI2(HC), HI2(DQ[2]), E1);
        EFMA(LO2(HD), LO2(DQ[3]), E0); EFMA(HI2(HD), HI2(DQ[3]), E1);
        f32x2 E = E0 + E1;
        float d = E.x + E.y;
        d = dpp_add<RR8>(dpp_add<QP_2301>(dpp_add<QP_1032>(d)));
        if (dlane) outd[(S_ - 1) * V_] = d + db;
    }
}

extern "C" void kernel_launch(void* const* d_in, const int* in_sizes, int n_in,
                              void* d_out, int out_size, void* d_ws, size_t ws_size,
                              hipStream_t stream) {
    const int*   enc_ids = (const int*)d_in[0];
    const int*   dec_ids = (const int*)d_in[1];
    const float* embed   = (const float*)d_in[2];
    const float* enc_Wx  = (const float*)d_in[3];
    const float* enc_Wh  = (const float*)d_in[4];
    const float* enc_b   = (const float*)d_in[5];
    const float* dec_Wx  = (const float*)d_in[6];
    const float* dec_Wh  = (const float*)d_in[7];
    const float* dec_b   = (const float*)d_in[8];
    const float* dense_W = (const float*)d_in[9];
    const float* dense_b = (const float*)d_in[10];
    float* out = (float*)d_out;
    float* Tg  = (float*)d_ws;   // 2*27*128 floats = 27648 B

    hipLaunchKernelGGL(prep_T, dim3(2 * V_), dim3(H_), 0, stream,
                       embed, enc_Wx, enc_b, dec_Wx, dec_b, Tg);
    hipLaunchKernelGGL(seq2seq_rnn_kernel, dim3(256), dim3(256), 0, stream,
                       enc_ids, dec_ids, enc_Wh, dec_Wh, dense_W, dense_b, Tg, out);
}